// Round 18
// baseline (427.282 us; speedup 1.0000x reference)
//
#include <hip/hip_runtime.h>

#define D 128
#define NC 40
#define BSHIFT 10            // 1024 nodes per dst-bucket

typedef __attribute__((ext_vector_type(8))) short short8v;
typedef __attribute__((ext_vector_type(4))) float f32x4;

__device__ __forceinline__ unsigned short f2bf(float f) {
    unsigned u = __float_as_uint(f);
    u += 0x7fff + ((u >> 16) & 1);          // RNE
    return (unsigned short)(u >> 16);
}
__device__ __forceinline__ float bf2f(unsigned short h) {
    return __uint_as_float(((unsigned)h) << 16);
}

__device__ __forceinline__ int load_idx(const int* ei, long long pos, int is64) {
    return is64 ? ei[pos * 2] : ei[pos];
}

// per-wave int64-vs-int32 detection: check high dwords of first 64 entries
__device__ __forceinline__ int detect64(const int* __restrict__ ei) {
    int lane = threadIdx.x & 63;
    int hi = ei[lane * 2 + 1];
    return __any(hi != 0) ? 0 : 1;
}

// ---------------- graph build (bucketed CSR) ----------------

// Phase A: partition edges into dst-buckets (dense writes) + weight conversion
__launch_bounds__(1024)
__global__ void bucket_kernel(const int* __restrict__ ei, int E, int EB, int NBK, int cap,
                              int2* __restrict__ ebuf, int* __restrict__ bcur,
                              const float* __restrict__ W1, const float* __restrict__ Wh,
                              const float* __restrict__ Wf,
                              unsigned short* __restrict__ Wc1, unsigned short* __restrict__ Wch0,
                              unsigned short* __restrict__ Wch1, unsigned short* __restrict__ Wcf) {
    if ((int)blockIdx.x < EB) {
        __shared__ int lhist[64], lbase[64], lcur[64];
        int t = threadIdx.x;
        int is64 = detect64(ei);
        int e = blockIdx.x * 1024 + t;
        int src = 0, dst = 0, b = -1;
        if (e < E) {
            src = load_idx(ei, (long long)e, is64);
            dst = load_idx(ei, (long long)E + e, is64);
            b = dst >> BSHIFT;
        }
        if (t < 64) { lhist[t] = 0; lcur[t] = 0; }
        __syncthreads();
        if (b >= 0) atomicAdd(&lhist[b], 1);
        __syncthreads();
        if (t < NBK && lhist[t] > 0) lbase[t] = atomicAdd(&bcur[t], lhist[t]);
        __syncthreads();
        if (b >= 0) {
            int idx = atomicAdd(&lcur[b], 1);
            int pos = lbase[b] + idx;
            if (pos < cap) ebuf[(size_t)b * cap + pos] = make_int2(src, dst);
        }
    } else {
        int idx = ((int)blockIdx.x - EB) * 1024 + (int)threadIdx.x;   // 0 .. 55295
        if (idx < 49152) {
            int which = idx >> 14;                           // 0,1,2
            int j = idx & 16383;
            int nn = j >> 7, k = j & 127;
            const float* W = (which == 0) ? W1 : (which == 1) ? Wh : Wh + 16384;
            unsigned short* o = (which == 0) ? Wc1 : (which == 1) ? Wch0 : Wch1;
            float v = W[k * 128 + nn];
            unsigned short h = f2bf(v);
            o[j] = h;
            o[16384 + j] = f2bf(v - bf2f(h));
        } else if (idx < 49152 + 6144) {
            int j = idx - 49152;
            int nn = j >> 7, k = j & 127;
            float v = (nn < NC) ? Wf[k * NC + nn] : 0.f;
            unsigned short h = f2bf(v);
            Wcf[j] = h;
            Wcf[6144 + j] = f2bf(v - bf2f(h));
        }
    }
}

// bucket-local degree count: atomics confined to a 4KB deg window per bucket
__launch_bounds__(1024)
__global__ void count_bucket_kernel(const int2* __restrict__ ebuf, const int* __restrict__ bcur,
                                    int* __restrict__ deg, int cap, int SPLIT) {
    int b = blockIdx.x / SPLIT, p = blockIdx.x % SPLIT;
    int sz = bcur[b]; if (sz > cap) sz = cap;
    int chunk = (sz + SPLIT - 1) / SPLIT;
    int s0 = p * chunk, s1 = s0 + chunk; if (s1 > sz) s1 = sz;
    for (int i = s0 + (int)threadIdx.x; i < s1; i += 1024)
        atomicAdd(&deg[ebuf[(size_t)b * cap + i].y], 1);
}

// phase 1: per-block (512) sums of deg
__global__ void scan1_kernel(const int* __restrict__ deg, int* __restrict__ bsum, int m) {
    int i = blockIdx.x * 512 + threadIdx.x;
    int v = (i < m) ? deg[i] : 0;
    #pragma unroll
    for (int off = 32; off; off >>= 1) v += __shfl_down(v, off, 64);
    __shared__ int ws[8];
    if ((threadIdx.x & 63) == 0) ws[threadIdx.x >> 6] = v;
    __syncthreads();
    if (threadIdx.x == 0) {
        int s = 0;
        #pragma unroll
        for (int j = 0; j < 8; ++j) s += ws[j];
        bsum[blockIdx.x] = s;
    }
}

// phase 2: inline prefix over bsum + local scan + emit rowptr/fill/dinv
__global__ void scan3_kernel(const int* __restrict__ deg, const int* __restrict__ bsum,
                             int* __restrict__ rowptr, int* __restrict__ fill,
                             float* __restrict__ dinv, int n, int E, int nb) {
    int t = threadIdx.x;                       // 512
    int lane = t & 63, w = t >> 6;
    int pv = (t < nb && t < (int)blockIdx.x) ? bsum[t] : 0;
    int rs = pv;
    #pragma unroll
    for (int off = 32; off; off >>= 1) rs += __shfl_down(rs, off, 64);
    __shared__ int red[8];
    if (lane == 0) red[w] = rs;
    __syncthreads();
    int base = 0;
    #pragma unroll
    for (int j = 0; j < 8; ++j) base += red[j];
    __syncthreads();

    int i = blockIdx.x * 512 + t;
    int v = (i < n) ? deg[i] : 0;
    int s = v;
    #pragma unroll
    for (int off = 1; off < 64; off <<= 1) {
        int x = __shfl_up(s, off, 64);
        if (lane >= off) s += x;
    }
    __shared__ int wsum[8];
    if (lane == 63) wsum[w] = s;
    __syncthreads();
    int wbase = 0;
    #pragma unroll
    for (int j = 0; j < 8; ++j) if (j < w) wbase += wsum[j];
    int excl = base + wbase + s - v;
    if (i < n) {
        rowptr[i] = excl;
        fill[i]   = excl;
        dinv[i]   = rsqrtf((float)(v + 1));   // +1 self loop
    }
    if (i == 0) rowptr[n] = E;
}

// bucket-local CSR scatter
__launch_bounds__(1024)
__global__ void scatter_bucket_kernel(const int2* __restrict__ ebuf, const int* __restrict__ bcur,
                                      int* __restrict__ fill, const float* __restrict__ dinv,
                                      int2* __restrict__ col2, int cap, int SPLIT) {
    int b = blockIdx.x / SPLIT, p = blockIdx.x % SPLIT;
    int sz = bcur[b]; if (sz > cap) sz = cap;
    int chunk = (sz + SPLIT - 1) / SPLIT;
    int s0 = p * chunk, s1 = s0 + chunk; if (s1 > sz) s1 = sz;
    for (int i = s0 + (int)threadIdx.x; i < s1; i += 1024) {
        int2 sd = ebuf[(size_t)b * cap + i];
        int pos = atomicAdd(&fill[sd.y], 1);
        col2[pos] = make_int2(sd.x, __float_as_int(dinv[sd.x]));
    }
}

// ---------------- 8-way column-slice aggregate (L2-resident per XCD) --------
// Block computes ONE 16-col slice for 64 nodes. blockIdx&7 = XCD (round-robin
// heuristic, locality-only): XCD k owns col slice k -> per-XCD h working set
// 50000 x 64B = 3.2MB < 4MB L2, so gathers become L2 hits after first touch.
// 4 lanes x float4 per node still fetch one full 64B line per edge.
// Emits raw normalized aggregate as bf16 hi/lo planes; bias/relu in transform.
__launch_bounds__(256)
__global__ void agg_slice_kernel(const float4* __restrict__ h4, const float* __restrict__ dinv,
                                 const int* __restrict__ rowptr, const int2* __restrict__ col2,
                                 ushort4* __restrict__ outHi, ushort4* __restrict__ outLo,
                                 int n, int T) {
    int b = blockIdx.x;
    int slice = b & 7;                   // XCD affinity: 1/8 col slice
    int tile = b >> 3;                   // 64-node tile
    if (tile >= T) return;
    int g = threadIdx.x >> 2, li = threadIdx.x & 3;   // node-in-tile, lane-in-node
    int node = tile * 64 + g;
    if (node >= n) return;
    float dn = dinv[node];
    int cbase = slice * 4 + li;          // float4 index within the 32-float4 row
    size_t rowoff = (size_t)node * 32 + cbase;
    float4 hv = h4[rowoff];
    float4 acc;
    acc.x = hv.x * dn; acc.y = hv.y * dn; acc.z = hv.z * dn; acc.w = hv.w * dn;
    int e = rowptr[node], e1 = rowptr[node + 1];
    for (; e + 8 <= e1; e += 8) {
        int2 c[8];
        #pragma unroll
        for (int q = 0; q < 8; ++q) c[q] = col2[e + q];
        float4 v[8];
        #pragma unroll
        for (int q = 0; q < 8; ++q) v[q] = h4[(size_t)c[q].x * 32 + cbase];
        #pragma unroll
        for (int q = 0; q < 8; ++q) {
            float ds = __int_as_float(c[q].y);
            acc.x += v[q].x * ds; acc.y += v[q].y * ds;
            acc.z += v[q].z * ds; acc.w += v[q].w * ds;
        }
    }
    for (; e + 4 <= e1; e += 4) {
        int2 c[4];
        #pragma unroll
        for (int q = 0; q < 4; ++q) c[q] = col2[e + q];
        float4 v[4];
        #pragma unroll
        for (int q = 0; q < 4; ++q) v[q] = h4[(size_t)c[q].x * 32 + cbase];
        #pragma unroll
        for (int q = 0; q < 4; ++q) {
            float ds = __int_as_float(c[q].y);
            acc.x += v[q].x * ds; acc.y += v[q].y * ds;
            acc.z += v[q].z * ds; acc.w += v[q].w * ds;
        }
    }
    for (; e < e1; ++e) {
        int2 c = col2[e];
        float ds = __int_as_float(c.y);
        float4 v = h4[(size_t)c.x * 32 + cbase];
        acc.x += v.x * ds; acc.y += v.y * ds; acc.z += v.z * ds; acc.w += v.w * ds;
    }
    acc.x *= dn; acc.y *= dn; acc.z *= dn; acc.w *= dn;
    ushort4 hi, lo;
    hi.x = f2bf(acc.x); lo.x = f2bf(acc.x - bf2f(hi.x));
    hi.y = f2bf(acc.y); lo.y = f2bf(acc.y - bf2f(hi.y));
    hi.z = f2bf(acc.z); lo.z = f2bf(acc.z - bf2f(hi.z));
    hi.w = f2bf(acc.w); lo.w = f2bf(acc.w - bf2f(hi.w));
    outHi[rowoff] = hi;
    outLo[rowoff] = lo;
}

// ---------------- transform: h_out = relu( A @ W + b ), 64-row tiles --------
// A arrives as bf16 hi/lo planes (pure-copy swizzled staging).
// FINAL=1: also compute out = relu(...)@Wf + bf in-block, writing d_out.
template<int FINAL>
__launch_bounds__(256)
__global__ void transform_kernel(const unsigned short* __restrict__ Ahi_g,
                                 const unsigned short* __restrict__ Alo_g,
                                 const unsigned short* __restrict__ Wcvt,  // [128n][128k] hi,lo
                                 const float* __restrict__ bias,
                                 float* __restrict__ out,
                                 const unsigned short* __restrict__ Wfc,   // [48n][128k] hi,lo
                                 const float* __restrict__ bf,
                                 float* __restrict__ outF, int M) {
    __shared__ unsigned short Ah[64 * 128];   // 16KB swizzled [row][k]
    __shared__ unsigned short Al[64 * 128];   // 16KB
    int t = threadIdx.x;
    int l = t & 63, w = t >> 6;
    int lr = l & 15, lh = l >> 4;

    int row0 = blockIdx.x * 64;
    #pragma unroll
    for (int c = 0; c < 4; ++c) {
        int chunk = c * 256 + t;
        int r  = chunk >> 4;
        int kc = chunk & 15;
        int gr = row0 + r; if (gr >= M) gr = M - 1;
        int off = (r << 8) + ((kc << 4) ^ ((r & 7) << 4));
        *(short8v*)((char*)Ah + off) = *(const short8v*)&Ahi_g[(size_t)gr * 128 + kc * 8];
        *(short8v*)((char*)Al + off) = *(const short8v*)&Alo_g[(size_t)gr * 128 + kc * 8];
    }
    __syncthreads();

    const unsigned short* Whi = Wcvt;
    const unsigned short* Wlo = Wcvt + 128 * 128;
    short8v bh[2][4], bl[2][4];
    int n0 = w * 32;
    #pragma unroll
    for (int ni = 0; ni < 2; ++ni) {
        int nn = n0 + ni * 16 + lr;
        #pragma unroll
        for (int ks = 0; ks < 4; ++ks) {
            bh[ni][ks] = *(const short8v*)&Whi[nn * 128 + ks * 32 + lh * 8];
            bl[ni][ks] = *(const short8v*)&Wlo[nn * 128 + ks * 32 + lh * 8];
        }
    }

    f32x4 acc[4][2];
    #pragma unroll
    for (int mi = 0; mi < 4; ++mi)
        #pragma unroll
        for (int ni = 0; ni < 2; ++ni)
            acc[mi][ni] = (f32x4){0.f, 0.f, 0.f, 0.f};

    #pragma unroll
    for (int mi = 0; mi < 4; ++mi) {
        int row = mi * 16 + lr;
        #pragma unroll
        for (int ks = 0; ks < 4; ++ks) {
            int off = (row << 8) + (((ks << 6) + (lh << 4)) ^ ((row & 7) << 4));
            short8v ah = *(short8v*)((char*)Ah + off);
            short8v al = *(short8v*)((char*)Al + off);
            #pragma unroll
            for (int ni = 0; ni < 2; ++ni) {
                acc[mi][ni] = __builtin_amdgcn_mfma_f32_16x16x32_bf16(ah, bh[ni][ks], acc[mi][ni], 0, 0, 0);
                acc[mi][ni] = __builtin_amdgcn_mfma_f32_16x16x32_bf16(ah, bl[ni][ks], acc[mi][ni], 0, 0, 0);
                acc[mi][ni] = __builtin_amdgcn_mfma_f32_16x16x32_bf16(al, bh[ni][ks], acc[mi][ni], 0, 0, 0);
            }
        }
    }

    if constexpr (!FINAL) {
        #pragma unroll
        for (int mi = 0; mi < 4; ++mi) {
            #pragma unroll
            for (int ni = 0; ni < 2; ++ni) {
                float bv = bias[n0 + ni * 16 + lr];
                #pragma unroll
                for (int r = 0; r < 4; ++r) {
                    int row = row0 + mi * 16 + lh * 4 + r;
                    if (row < M)
                        out[(size_t)row * 128 + n0 + ni * 16 + lr] = fmaxf(acc[mi][ni][r] + bv, 0.f);
                }
            }
        }
    } else {
        // h3 = relu(acc + bias); restage to LDS planes; 48-col Wf MFMA -> outF
        __syncthreads();   // all transform A-reads done before overwrite
        #pragma unroll
        for (int mi = 0; mi < 4; ++mi) {
            #pragma unroll
            for (int ni = 0; ni < 2; ++ni) {
                float bv = bias[n0 + ni * 16 + lr];
                int colc = n0 + ni * 16 + lr;
                #pragma unroll
                for (int r = 0; r < 4; ++r) {
                    float v = fmaxf(acc[mi][ni][r] + bv, 0.f);
                    unsigned short hv = f2bf(v);
                    unsigned short lv = f2bf(v - bf2f(hv));
                    int row = mi * 16 + lh * 4 + r;
                    int boff = (row << 8) + ((2 * colc) ^ ((row & 7) << 4));
                    *(unsigned short*)((char*)Ah + boff) = hv;
                    *(unsigned short*)((char*)Al + boff) = lv;
                }
            }
        }
        __syncthreads();
        const unsigned short* Fhi = Wfc;
        const unsigned short* Flo = Wfc + 48 * 128;
        #pragma unroll
        for (int nt = 0; nt < 3; ++nt) {
            int col48 = nt * 16 + lr;
            short8v fh[4], fl[4];
            #pragma unroll
            for (int ks = 0; ks < 4; ++ks) {
                fh[ks] = *(const short8v*)&Fhi[col48 * 128 + ks * 32 + lh * 8];
                fl[ks] = *(const short8v*)&Flo[col48 * 128 + ks * 32 + lh * 8];
            }
            f32x4 of = (f32x4){0.f, 0.f, 0.f, 0.f};
            #pragma unroll
            for (int ks = 0; ks < 4; ++ks) {
                int arow = w * 16 + lr;
                int aoff = (arow << 8) + (((ks << 6) + (lh << 4)) ^ ((arow & 7) << 4));
                short8v ah = *(short8v*)((char*)Ah + aoff);
                short8v al = *(short8v*)((char*)Al + aoff);
                of = __builtin_amdgcn_mfma_f32_16x16x32_bf16(ah, fh[ks], of, 0, 0, 0);
                of = __builtin_amdgcn_mfma_f32_16x16x32_bf16(ah, fl[ks], of, 0, 0, 0);
                of = __builtin_amdgcn_mfma_f32_16x16x32_bf16(al, fh[ks], of, 0, 0, 0);
            }
            float bfv = (col48 < NC) ? bf[col48] : 0.f;
            #pragma unroll
            for (int r = 0; r < 4; ++r) {
                int ro = row0 + w * 16 + lh * 4 + r;
                if (col48 < NC && ro < M)
                    outF[(size_t)ro * NC + col48] = of[r] + bfv;
            }
        }
    }
}

extern "C" void kernel_launch(void* const* d_in, const int* in_sizes, int n_in,
                              void* d_out, int out_size, void* d_ws, size_t ws_size,
                              hipStream_t stream) {
    const float* x  = (const float*)d_in[0];
    const int*   ei = (const int*)d_in[1];
    const float* W1 = (const float*)d_in[2];
    const float* b1 = (const float*)d_in[3];
    const float* Wh = (const float*)d_in[4];
    const float* bh = (const float*)d_in[5];
    const float* Wf = (const float*)d_in[6];
    const float* bf = (const float*)d_in[7];
    float* out = (float*)d_out;

    int n = in_sizes[0] / D;    // 50000
    int E = in_sizes[1] / 2;    // 800000
    int NBK = (n + (1 << BSHIFT) - 1) >> BSHIFT;   // 49
    int per = E / NBK;
    int cap = per + per / 4 + 2048;

    char* ws = (char*)d_ws;
    size_t off = 0;
    auto alloc = [&](size_t bytes) {
        void* p = ws + off;
        off = (off + bytes + 255) & ~(size_t)255;
        return p;
    };
    float* B0     = (float*)alloc((size_t)n * D * 4);
    float* B1     = (float*)alloc((size_t)n * D * 4);
    unsigned short* Bhi = (unsigned short*)alloc((size_t)n * D * 2);
    unsigned short* Blo = (unsigned short*)alloc((size_t)n * D * 2);
    int*   deg    = (int*)alloc((size_t)n * 4);
    int*   rowptr = (int*)alloc((size_t)(n + 1) * 4);
    int*   fill   = (int*)alloc((size_t)n * 4);
    int2*  col2   = (int2*)alloc((size_t)E * 8);
    float* dinv   = (float*)alloc((size_t)n * 4);
    int*   bsum   = (int*)alloc(1024 * 4);
    int2*  ebuf   = (int2*)alloc((size_t)NBK * cap * 8);
    int*   bcur   = (int*)alloc(64 * 4);
    unsigned short* Wc1  = (unsigned short*)alloc(2 * 128 * 128 * 2);
    unsigned short* Wch0 = (unsigned short*)alloc(2 * 128 * 128 * 2);
    unsigned short* Wch1 = (unsigned short*)alloc(2 * 128 * 128 * 2);
    unsigned short* Wcf  = (unsigned short*)alloc(2 * 48 * 128 * 2);

    int EB = (E + 1023) / 1024;                 // 782 edge blocks
    int CB = (49152 + 6144 + 1023) / 1024;      // 54 convert blocks
    int nb = (n + 511) / 512;                   // 98
    int SPLIT = 8;

    hipMemsetAsync(deg, 0, (size_t)n * 4, stream);
    hipMemsetAsync(bcur, 0, 64 * 4, stream);
    bucket_kernel<<<EB + CB, 1024, 0, stream>>>(ei, E, EB, NBK, cap, ebuf, bcur,
                                                W1, Wh, Wf, Wc1, Wch0, Wch1, Wcf);
    count_bucket_kernel<<<NBK * SPLIT, 1024, 0, stream>>>(ebuf, bcur, deg, cap, SPLIT);
    scan1_kernel<<<nb, 512, 0, stream>>>(deg, bsum, n);
    scan3_kernel<<<nb, 512, 0, stream>>>(deg, bsum, rowptr, fill, dinv, n, E, nb);
    scatter_bucket_kernel<<<NBK * SPLIT, 1024, 0, stream>>>(ebuf, bcur, fill, dinv, col2, cap, SPLIT);

    int T = (n + 63) / 64;                // 64-node tiles
    int agrid = T * 8;                    // one block per (tile, col-slice)
    int tgrid = (n + 63) / 64;

    agg_slice_kernel<<<agrid, 256, 0, stream>>>((const float4*)x, dinv, rowptr, col2,
                                                (ushort4*)Bhi, (ushort4*)Blo, n, T);
    transform_kernel<0><<<tgrid, 256, 0, stream>>>(Bhi, Blo, Wc1, b1, B0, Wcf, bf, out, n);
    agg_slice_kernel<<<agrid, 256, 0, stream>>>((const float4*)B0, dinv, rowptr, col2,
                                                (ushort4*)Bhi, (ushort4*)Blo, n, T);
    transform_kernel<0><<<tgrid, 256, 0, stream>>>(Bhi, Blo, Wch0, bh, B1, Wcf, bf, out, n);
    agg_slice_kernel<<<agrid, 256, 0, stream>>>((const float4*)B1, dinv, rowptr, col2,
                                                (ushort4*)Bhi, (ushort4*)Blo, n, T);
    transform_kernel<1><<<tgrid, 256, 0, stream>>>(Bhi, Blo, Wch1, bh + D, B0, Wcf, bf, out, n);
}

// Round 19
// 306.964 us; speedup vs baseline: 1.3920x; 1.3920x over previous
//
#include <hip/hip_runtime.h>

#define D 128
#define NC 40
#define BSHIFT 10            // 1024 nodes per dst-bucket

typedef __attribute__((ext_vector_type(8))) short short8v;
typedef __attribute__((ext_vector_type(4))) float f32x4;

__device__ __forceinline__ unsigned short f2bf(float f) {
    unsigned u = __float_as_uint(f);
    u += 0x7fff + ((u >> 16) & 1);          // RNE
    return (unsigned short)(u >> 16);
}
__device__ __forceinline__ float bf2f(unsigned short h) {
    return __uint_as_float(((unsigned)h) << 16);
}

__device__ __forceinline__ int load_idx(const int* ei, long long pos, int is64) {
    return is64 ? ei[pos * 2] : ei[pos];
}

// per-wave int64-vs-int32 detection: check high dwords of first 64 entries
__device__ __forceinline__ int detect64(const int* __restrict__ ei) {
    int lane = threadIdx.x & 63;
    int hi = ei[lane * 2 + 1];
    return __any(hi != 0) ? 0 : 1;
}

// ---------------- graph build (bucketed CSR) ----------------

// Phase A: partition edges into dst-buckets (dense writes) + weight conversion
// + deg zeroing in tail blocks (deg only consumed by the NEXT kernel, so
// block-order independent — saves a memset launch).
__launch_bounds__(1024)
__global__ void bucket_kernel(const int* __restrict__ ei, int E, int EB, int NBK, int cap,
                              int2* __restrict__ ebuf, int* __restrict__ bcur,
                              int* __restrict__ deg, int n,
                              const float* __restrict__ W1, const float* __restrict__ Wh,
                              const float* __restrict__ Wf,
                              unsigned short* __restrict__ Wc1, unsigned short* __restrict__ Wch0,
                              unsigned short* __restrict__ Wch1, unsigned short* __restrict__ Wcf) {
    if ((int)blockIdx.x < EB) {
        __shared__ int lhist[64], lbase[64], lcur[64];
        int t = threadIdx.x;
        int is64 = detect64(ei);
        int e = blockIdx.x * 1024 + t;
        int src = 0, dst = 0, b = -1;
        if (e < E) {
            src = load_idx(ei, (long long)e, is64);
            dst = load_idx(ei, (long long)E + e, is64);
            b = dst >> BSHIFT;
        }
        if (t < 64) { lhist[t] = 0; lcur[t] = 0; }
        __syncthreads();
        if (b >= 0) atomicAdd(&lhist[b], 1);
        __syncthreads();
        if (t < NBK && lhist[t] > 0) lbase[t] = atomicAdd(&bcur[t], lhist[t]);
        __syncthreads();
        if (b >= 0) {
            int idx = atomicAdd(&lcur[b], 1);
            int pos = lbase[b] + idx;
            if (pos < cap) ebuf[(size_t)b * cap + pos] = make_int2(src, dst);
        }
    } else {
        int idx = ((int)blockIdx.x - EB) * 1024 + (int)threadIdx.x;   // 0 .. 55295 (=54*1024)
        if (idx < 49152) {
            int which = idx >> 14;                           // 0,1,2
            int j = idx & 16383;
            int nn = j >> 7, k = j & 127;
            const float* W = (which == 0) ? W1 : (which == 1) ? Wh : Wh + 16384;
            unsigned short* o = (which == 0) ? Wc1 : (which == 1) ? Wch0 : Wch1;
            float v = W[k * 128 + nn];
            unsigned short h = f2bf(v);
            o[j] = h;
            o[16384 + j] = f2bf(v - bf2f(h));
        } else if (idx < 49152 + 6144) {
            int j = idx - 49152;
            int nn = j >> 7, k = j & 127;
            float v = (nn < NC) ? Wf[k * NC + nn] : 0.f;
            unsigned short h = f2bf(v);
            Wcf[j] = h;
            Wcf[6144 + j] = f2bf(v - bf2f(h));
        } else {
            int j = idx - 55296;          // deg zeroing tail
            if (j < n) deg[j] = 0;
        }
    }
}

// bucket-local degree count: atomics confined to a 4KB deg window per bucket
__launch_bounds__(1024)
__global__ void count_bucket_kernel(const int2* __restrict__ ebuf, const int* __restrict__ bcur,
                                    int* __restrict__ deg, int cap, int SPLIT) {
    int b = blockIdx.x / SPLIT, p = blockIdx.x % SPLIT;
    int sz = bcur[b]; if (sz > cap) sz = cap;
    int chunk = (sz + SPLIT - 1) / SPLIT;
    int s0 = p * chunk, s1 = s0 + chunk; if (s1 > sz) s1 = sz;
    for (int i = s0 + (int)threadIdx.x; i < s1; i += 1024)
        atomicAdd(&deg[ebuf[(size_t)b * cap + i].y], 1);
}

// phase 1: per-block (512) sums of deg
__global__ void scan1_kernel(const int* __restrict__ deg, int* __restrict__ bsum, int m) {
    int i = blockIdx.x * 512 + threadIdx.x;
    int v = (i < m) ? deg[i] : 0;
    #pragma unroll
    for (int off = 32; off; off >>= 1) v += __shfl_down(v, off, 64);
    __shared__ int ws[8];
    if ((threadIdx.x & 63) == 0) ws[threadIdx.x >> 6] = v;
    __syncthreads();
    if (threadIdx.x == 0) {
        int s = 0;
        #pragma unroll
        for (int j = 0; j < 8; ++j) s += ws[j];
        bsum[blockIdx.x] = s;
    }
}

// phase 2: inline prefix over bsum + local scan + emit rowptr/fill/dinv
__global__ void scan3_kernel(const int* __restrict__ deg, const int* __restrict__ bsum,
                             int* __restrict__ rowptr, int* __restrict__ fill,
                             float* __restrict__ dinv, int n, int E, int nb) {
    int t = threadIdx.x;                       // 512
    int lane = t & 63, w = t >> 6;
    int pv = (t < nb && t < (int)blockIdx.x) ? bsum[t] : 0;
    int rs = pv;
    #pragma unroll
    for (int off = 32; off; off >>= 1) rs += __shfl_down(rs, off, 64);
    __shared__ int red[8];
    if (lane == 0) red[w] = rs;
    __syncthreads();
    int base = 0;
    #pragma unroll
    for (int j = 0; j < 8; ++j) base += red[j];
    __syncthreads();

    int i = blockIdx.x * 512 + t;
    int v = (i < n) ? deg[i] : 0;
    int s = v;
    #pragma unroll
    for (int off = 1; off < 64; off <<= 1) {
        int x = __shfl_up(s, off, 64);
        if (lane >= off) s += x;
    }
    __shared__ int wsum[8];
    if (lane == 63) wsum[w] = s;
    __syncthreads();
    int wbase = 0;
    #pragma unroll
    for (int j = 0; j < 8; ++j) if (j < w) wbase += wsum[j];
    int excl = base + wbase + s - v;
    if (i < n) {
        rowptr[i] = excl;
        fill[i]   = excl;
        dinv[i]   = rsqrtf((float)(v + 1));   // +1 self loop
    }
    if (i == 0) rowptr[n] = E;
}

// bucket-local CSR scatter
__launch_bounds__(1024)
__global__ void scatter_bucket_kernel(const int2* __restrict__ ebuf, const int* __restrict__ bcur,
                                      int* __restrict__ fill, const float* __restrict__ dinv,
                                      int2* __restrict__ col2, int cap, int SPLIT) {
    int b = blockIdx.x / SPLIT, p = blockIdx.x % SPLIT;
    int sz = bcur[b]; if (sz > cap) sz = cap;
    int chunk = (sz + SPLIT - 1) / SPLIT;
    int s0 = p * chunk, s1 = s0 + chunk; if (s1 > sz) s1 = sz;
    for (int i = s0 + (int)threadIdx.x; i < s1; i += 1024) {
        int2 sd = ebuf[(size_t)b * cap + i];
        int pos = atomicAdd(&fill[sd.y], 1);
        col2[pos] = make_int2(sd.x, __float_as_int(dinv[sd.x]));
    }
}

// ---------------- 2-way column-split aggregate (r17-proven), plane output ---
// Block computes ONE 64-column half for 16 nodes; per-XCD working set halves
// (robust to sloppy block->XCD mapping, unlike 8-way slicing which regressed).
// Emits raw normalized aggregate as bf16 hi/lo planes; bias/relu in transform.
__launch_bounds__(256)
__global__ void agg_half_kernel(const float4* __restrict__ h4, const float* __restrict__ dinv,
                                const int* __restrict__ rowptr, const int2* __restrict__ col2,
                                ushort4* __restrict__ outHi, ushort4* __restrict__ outLo,
                                int n, int T) {
    int b = blockIdx.x;
    int xcd = b & 7;
    int half = xcd >> 2;                 // 0 or 1
    int tile = (b >> 3) * 4 + (xcd & 3);
    if (tile >= T) return;
    int g = threadIdx.x >> 4, li = threadIdx.x & 15;
    int node = tile * 16 + g;
    if (node >= n) return;
    float dn = dinv[node];
    size_t rowoff = (size_t)node * 32 + half * 16 + li;
    float4 hv = h4[rowoff];
    float4 acc;
    acc.x = hv.x * dn; acc.y = hv.y * dn; acc.z = hv.z * dn; acc.w = hv.w * dn;
    int e = rowptr[node], e1 = rowptr[node + 1];
    int cbase = half * 16 + li;
    for (; e + 8 <= e1; e += 8) {
        int2 c[8];
        #pragma unroll
        for (int q = 0; q < 8; ++q) c[q] = col2[e + q];
        float4 v[8];
        #pragma unroll
        for (int q = 0; q < 8; ++q) v[q] = h4[(size_t)c[q].x * 32 + cbase];
        #pragma unroll
        for (int q = 0; q < 8; ++q) {
            float ds = __int_as_float(c[q].y);
            acc.x += v[q].x * ds; acc.y += v[q].y * ds;
            acc.z += v[q].z * ds; acc.w += v[q].w * ds;
        }
    }
    for (; e + 4 <= e1; e += 4) {
        int2 c[4];
        #pragma unroll
        for (int q = 0; q < 4; ++q) c[q] = col2[e + q];
        float4 v[4];
        #pragma unroll
        for (int q = 0; q < 4; ++q) v[q] = h4[(size_t)c[q].x * 32 + cbase];
        #pragma unroll
        for (int q = 0; q < 4; ++q) {
            float ds = __int_as_float(c[q].y);
            acc.x += v[q].x * ds; acc.y += v[q].y * ds;
            acc.z += v[q].z * ds; acc.w += v[q].w * ds;
        }
    }
    for (; e < e1; ++e) {
        int2 c = col2[e];
        float ds = __int_as_float(c.y);
        float4 v = h4[(size_t)c.x * 32 + cbase];
        acc.x += v.x * ds; acc.y += v.y * ds; acc.z += v.z * ds; acc.w += v.w * ds;
    }
    acc.x *= dn; acc.y *= dn; acc.z *= dn; acc.w *= dn;
    ushort4 hi, lo;
    hi.x = f2bf(acc.x); lo.x = f2bf(acc.x - bf2f(hi.x));
    hi.y = f2bf(acc.y); lo.y = f2bf(acc.y - bf2f(hi.y));
    hi.z = f2bf(acc.z); lo.z = f2bf(acc.z - bf2f(hi.z));
    hi.w = f2bf(acc.w); lo.w = f2bf(acc.w - bf2f(hi.w));
    outHi[rowoff] = hi;
    outLo[rowoff] = lo;
}

// ---------------- transform: h_out = relu( A @ W + b ), 64-row tiles --------
// A arrives as bf16 hi/lo planes (pure-copy swizzled staging).
// FINAL=1: also compute out = relu(...)@Wf + bf in-block, writing d_out.
template<int FINAL>
__launch_bounds__(256)
__global__ void transform_kernel(const unsigned short* __restrict__ Ahi_g,
                                 const unsigned short* __restrict__ Alo_g,
                                 const unsigned short* __restrict__ Wcvt,  // [128n][128k] hi,lo
                                 const float* __restrict__ bias,
                                 float* __restrict__ out,
                                 const unsigned short* __restrict__ Wfc,   // [48n][128k] hi,lo
                                 const float* __restrict__ bf,
                                 float* __restrict__ outF, int M) {
    __shared__ unsigned short Ah[64 * 128];   // 16KB swizzled [row][k]
    __shared__ unsigned short Al[64 * 128];   // 16KB
    int t = threadIdx.x;
    int l = t & 63, w = t >> 6;
    int lr = l & 15, lh = l >> 4;

    int row0 = blockIdx.x * 64;
    #pragma unroll
    for (int c = 0; c < 4; ++c) {
        int chunk = c * 256 + t;
        int r  = chunk >> 4;
        int kc = chunk & 15;
        int gr = row0 + r; if (gr >= M) gr = M - 1;
        int off = (r << 8) + ((kc << 4) ^ ((r & 7) << 4));
        *(short8v*)((char*)Ah + off) = *(const short8v*)&Ahi_g[(size_t)gr * 128 + kc * 8];
        *(short8v*)((char*)Al + off) = *(const short8v*)&Alo_g[(size_t)gr * 128 + kc * 8];
    }
    __syncthreads();

    const unsigned short* Whi = Wcvt;
    const unsigned short* Wlo = Wcvt + 128 * 128;
    short8v bh[2][4], bl[2][4];
    int n0 = w * 32;
    #pragma unroll
    for (int ni = 0; ni < 2; ++ni) {
        int nn = n0 + ni * 16 + lr;
        #pragma unroll
        for (int ks = 0; ks < 4; ++ks) {
            bh[ni][ks] = *(const short8v*)&Whi[nn * 128 + ks * 32 + lh * 8];
            bl[ni][ks] = *(const short8v*)&Wlo[nn * 128 + ks * 32 + lh * 8];
        }
    }

    f32x4 acc[4][2];
    #pragma unroll
    for (int mi = 0; mi < 4; ++mi)
        #pragma unroll
        for (int ni = 0; ni < 2; ++ni)
            acc[mi][ni] = (f32x4){0.f, 0.f, 0.f, 0.f};

    #pragma unroll
    for (int mi = 0; mi < 4; ++mi) {
        int row = mi * 16 + lr;
        #pragma unroll
        for (int ks = 0; ks < 4; ++ks) {
            int off = (row << 8) + (((ks << 6) + (lh << 4)) ^ ((row & 7) << 4));
            short8v ah = *(short8v*)((char*)Ah + off);
            short8v al = *(short8v*)((char*)Al + off);
            #pragma unroll
            for (int ni = 0; ni < 2; ++ni) {
                acc[mi][ni] = __builtin_amdgcn_mfma_f32_16x16x32_bf16(ah, bh[ni][ks], acc[mi][ni], 0, 0, 0);
                acc[mi][ni] = __builtin_amdgcn_mfma_f32_16x16x32_bf16(ah, bl[ni][ks], acc[mi][ni], 0, 0, 0);
                acc[mi][ni] = __builtin_amdgcn_mfma_f32_16x16x32_bf16(al, bh[ni][ks], acc[mi][ni], 0, 0, 0);
            }
        }
    }

    if constexpr (!FINAL) {
        #pragma unroll
        for (int mi = 0; mi < 4; ++mi) {
            #pragma unroll
            for (int ni = 0; ni < 2; ++ni) {
                float bv = bias[n0 + ni * 16 + lr];
                #pragma unroll
                for (int r = 0; r < 4; ++r) {
                    int row = row0 + mi * 16 + lh * 4 + r;
                    if (row < M)
                        out[(size_t)row * 128 + n0 + ni * 16 + lr] = fmaxf(acc[mi][ni][r] + bv, 0.f);
                }
            }
        }
    } else {
        // h3 = relu(acc + bias); restage to LDS planes; 48-col Wf MFMA -> outF
        __syncthreads();   // all transform A-reads done before overwrite
        #pragma unroll
        for (int mi = 0; mi < 4; ++mi) {
            #pragma unroll
            for (int ni = 0; ni < 2; ++ni) {
                float bv = bias[n0 + ni * 16 + lr];
                int colc = n0 + ni * 16 + lr;
                #pragma unroll
                for (int r = 0; r < 4; ++r) {
                    float v = fmaxf(acc[mi][ni][r] + bv, 0.f);
                    unsigned short hv = f2bf(v);
                    unsigned short lv = f2bf(v - bf2f(hv));
                    int row = mi * 16 + lh * 4 + r;
                    int boff = (row << 8) + ((2 * colc) ^ ((row & 7) << 4));
                    *(unsigned short*)((char*)Ah + boff) = hv;
                    *(unsigned short*)((char*)Al + boff) = lv;
                }
            }
        }
        __syncthreads();
        const unsigned short* Fhi = Wfc;
        const unsigned short* Flo = Wfc + 48 * 128;
        #pragma unroll
        for (int nt = 0; nt < 3; ++nt) {
            int col48 = nt * 16 + lr;
            short8v fh[4], fl[4];
            #pragma unroll
            for (int ks = 0; ks < 4; ++ks) {
                fh[ks] = *(const short8v*)&Fhi[col48 * 128 + ks * 32 + lh * 8];
                fl[ks] = *(const short8v*)&Flo[col48 * 128 + ks * 32 + lh * 8];
            }
            f32x4 of = (f32x4){0.f, 0.f, 0.f, 0.f};
            #pragma unroll
            for (int ks = 0; ks < 4; ++ks) {
                int arow = w * 16 + lr;
                int aoff = (arow << 8) + (((ks << 6) + (lh << 4)) ^ ((arow & 7) << 4));
                short8v ah = *(short8v*)((char*)Ah + aoff);
                short8v al = *(short8v*)((char*)Al + aoff);
                of = __builtin_amdgcn_mfma_f32_16x16x32_bf16(ah, fh[ks], of, 0, 0, 0);
                of = __builtin_amdgcn_mfma_f32_16x16x32_bf16(ah, fl[ks], of, 0, 0, 0);
                of = __builtin_amdgcn_mfma_f32_16x16x32_bf16(al, fh[ks], of, 0, 0, 0);
            }
            float bfv = (col48 < NC) ? bf[col48] : 0.f;
            #pragma unroll
            for (int r = 0; r < 4; ++r) {
                int ro = row0 + w * 16 + lh * 4 + r;
                if (col48 < NC && ro < M)
                    outF[(size_t)ro * NC + col48] = of[r] + bfv;
            }
        }
    }
}

extern "C" void kernel_launch(void* const* d_in, const int* in_sizes, int n_in,
                              void* d_out, int out_size, void* d_ws, size_t ws_size,
                              hipStream_t stream) {
    const float* x  = (const float*)d_in[0];
    const int*   ei = (const int*)d_in[1];
    const float* W1 = (const float*)d_in[2];
    const float* b1 = (const float*)d_in[3];
    const float* Wh = (const float*)d_in[4];
    const float* bh = (const float*)d_in[5];
    const float* Wf = (const float*)d_in[6];
    const float* bf = (const float*)d_in[7];
    float* out = (float*)d_out;

    int n = in_sizes[0] / D;    // 50000
    int E = in_sizes[1] / 2;    // 800000
    int NBK = (n + (1 << BSHIFT) - 1) >> BSHIFT;   // 49
    int per = E / NBK;
    int cap = per + per / 4 + 2048;

    char* ws = (char*)d_ws;
    size_t off = 0;
    auto alloc = [&](size_t bytes) {
        void* p = ws + off;
        off = (off + bytes + 255) & ~(size_t)255;
        return p;
    };
    float* B0     = (float*)alloc((size_t)n * D * 4);
    float* B1     = (float*)alloc((size_t)n * D * 4);
    unsigned short* Bhi = (unsigned short*)alloc((size_t)n * D * 2);
    unsigned short* Blo = (unsigned short*)alloc((size_t)n * D * 2);
    int*   deg    = (int*)alloc((size_t)n * 4);
    int*   rowptr = (int*)alloc((size_t)(n + 1) * 4);
    int*   fill   = (int*)alloc((size_t)n * 4);
    int2*  col2   = (int2*)alloc((size_t)E * 8);
    float* dinv   = (float*)alloc((size_t)n * 4);
    int*   bsum   = (int*)alloc(1024 * 4);
    int2*  ebuf   = (int2*)alloc((size_t)NBK * cap * 8);
    int*   bcur   = (int*)alloc(64 * 4);
    unsigned short* Wc1  = (unsigned short*)alloc(2 * 128 * 128 * 2);
    unsigned short* Wch0 = (unsigned short*)alloc(2 * 128 * 128 * 2);
    unsigned short* Wch1 = (unsigned short*)alloc(2 * 128 * 128 * 2);
    unsigned short* Wcf  = (unsigned short*)alloc(2 * 48 * 128 * 2);

    int EB = (E + 1023) / 1024;                 // 782 edge blocks
    int DB = (n + 1023) / 1024;                 // 49 deg-zero blocks
    int CB = 54 + DB;                           // 54 convert blocks (55296=54*1024) + deg zero
    int nb = (n + 511) / 512;                   // 98
    int SPLIT = 8;

    hipMemsetAsync(bcur, 0, 64 * 4, stream);
    bucket_kernel<<<EB + CB, 1024, 0, stream>>>(ei, E, EB, NBK, cap, ebuf, bcur, deg, n,
                                                W1, Wh, Wf, Wc1, Wch0, Wch1, Wcf);
    count_bucket_kernel<<<NBK * SPLIT, 1024, 0, stream>>>(ebuf, bcur, deg, cap, SPLIT);
    scan1_kernel<<<nb, 512, 0, stream>>>(deg, bsum, n);
    scan3_kernel<<<nb, 512, 0, stream>>>(deg, bsum, rowptr, fill, dinv, n, E, nb);
    scatter_bucket_kernel<<<NBK * SPLIT, 1024, 0, stream>>>(ebuf, bcur, fill, dinv, col2, cap, SPLIT);

    int T = (n + 15) / 16;                // node tiles (16 nodes each)
    int agrid = ((T + 3) / 4) * 8;        // 4 tiles per 8-block XCD group
    int tgrid = (n + 63) / 64;

    agg_half_kernel<<<agrid, 256, 0, stream>>>((const float4*)x, dinv, rowptr, col2,
                                               (ushort4*)Bhi, (ushort4*)Blo, n, T);
    transform_kernel<0><<<tgrid, 256, 0, stream>>>(Bhi, Blo, Wc1, b1, B0, Wcf, bf, out, n);
    agg_half_kernel<<<agrid, 256, 0, stream>>>((const float4*)B0, dinv, rowptr, col2,
                                               (ushort4*)Bhi, (ushort4*)Blo, n, T);
    transform_kernel<0><<<tgrid, 256, 0, stream>>>(Bhi, Blo, Wch0, bh, B1, Wcf, bf, out, n);
    agg_half_kernel<<<agrid, 256, 0, stream>>>((const float4*)B1, dinv, rowptr, col2,
                                               (ushort4*)Bhi, (ushort4*)Blo, n, T);
    transform_kernel<1><<<tgrid, 256, 0, stream>>>(Bhi, Blo, Wch1, bh + D, B0, Wcf, bf, out, n);
}